// Round 22
// baseline (149.161 us; speedup 1.0000x reference)
//
#include <hip/hip_runtime.h>
#include <hip/hip_bf16.h>

#define N_NODES 100000
#define NUM_APS 1000
#define IN_F 32
#define HID 64
#define NB 391      // bins of 256 cols: 391*256 = 100096 >= N_NODES
#define EPB 4096    // edges per block (keeps ~10.5-record bin tails -> merged writes)
#define CAPB 4608   // per-bin staging capacity (mean 4092, +8 sigma), guarded
#define LISTCAP 24000
#define ZERON 100513  // binPtr(512) + acnt(1) + mark(100000)
#define G32 ((N_NODES * 4 + 255) / 256)  // 1563 gather blocks
#define ACTB 128                          // activeset tail blocks

typedef __hip_bfloat16 bf16;
typedef unsigned long long ull;
typedef __attribute__((ext_vector_type(8))) short bf16x8;
typedef __attribute__((ext_vector_type(4))) float f32x4;

__device__ __forceinline__ float b2f(bf16 v) { return __bfloat162float(v); }
__device__ __forceinline__ float blo(unsigned u) { return __uint_as_float(u << 16); }
__device__ __forceinline__ float bhi(unsigned u) { return __uint_as_float(u & 0xffff0000u); }
__device__ __forceinline__ unsigned packbf(float x, float y) {
    bf16 a = __float2bfloat16(x), b = __float2bfloat16(y);
    unsigned short ua = *reinterpret_cast<unsigned short*>(&a);
    unsigned short ub = *reinterpret_cast<unsigned short*>(&b);
    return (unsigned)ua | ((unsigned)ub << 16);
}
__device__ __forceinline__ short f2bs(float v) {
    bf16 t = __float2bfloat16(v);
    return *reinterpret_cast<short*>(&t);
}
// 4B edge record: r<<15 | q15(ew)
__device__ __forceinline__ unsigned rec_r(unsigned v) { return v >> 15; }
__device__ __forceinline__ float rec_w(unsigned v) { return (v & 32767u) * (1.f / 32768.f); }

// custom zero (rocclr fill has ~40 us fixed cost)
__global__ void zero_k(int* __restrict__ p) {
    int i = blockIdx.x * 256 + threadIdx.x;
    if (i < ZERON) p[i] = 0;
}

// ---------- binned CSR build, hist-free (verbatim round 21) ----------
__global__ __launch_bounds__(512) void binwrite2_k(const int* __restrict__ row,
                                                   const int* __restrict__ col,
                                                   const float* __restrict__ ew,
                                                   int* __restrict__ binPtr,
                                                   ull* __restrict__ staging, int E) {
    __shared__ int h1[NB];
    __shared__ int base[NB];
    __shared__ int h2[NB];
    for (int i = threadIdx.x; i < NB; i += 512) { h1[i] = 0; h2[i] = 0; }
    __syncthreads();
    int e0 = blockIdx.x * EPB, e1 = min(e0 + EPB, E);
    for (int e = e0 + threadIdx.x; e < e1; e += 512) atomicAdd(&h1[col[e] >> 8], 1);
    __syncthreads();
    for (int i = threadIdx.x; i < NB; i += 512) {
        int v = h1[i];
        base[i] = v ? atomicAdd(&binPtr[i], v) : 0;
    }
    __syncthreads();
    for (int e = e0 + threadIdx.x; e < e1; e += 512) {
        int c = col[e];
        int b = c >> 8;
        int slot = atomicAdd(&h2[b], 1);
        unsigned q = (unsigned)(ew[e] * 32768.0f + 0.5f);
        if (q > 32767u) q = 32767u;
        ull rec = ((ull)(unsigned)(c & 255) << 32) |
                  (ull)(((unsigned)row[e] << 15) | q);
        int pos = base[b] + slot;
        if (pos < CAPB) staging[(size_t)b * CAPB + pos] = rec;
    }
}

// binfin3: inlined bin-prefix (replaces binscan2) + bin sort + off/dinv + fused xs
__global__ __launch_bounds__(256) void binfin3_k(const ull* __restrict__ staging,
                                                 const int* __restrict__ binPtr,
                                                 const float* __restrict__ x,
                                                 unsigned* __restrict__ ed,
                                                 int* __restrict__ off,
                                                 float* __restrict__ dinv,
                                                 unsigned* __restrict__ xs) {
    __shared__ int sbp[NB];
    __shared__ unsigned cnt[256];
    __shared__ unsigned degq[256];
    __shared__ int wptr[256];
    __shared__ unsigned s[256];
    __shared__ float sdv[256];
    __shared__ int se0;
    int b = blockIdx.x;
    int tid = threadIdx.x;
    for (int i = tid; i < NB; i += 256) sbp[i] = min(binPtr[i], CAPB);
    cnt[tid] = 0;
    degq[tid] = 0;
    __syncthreads();
    // e0 = sum sbp[0..b): strided partials + tree reduce in s[]
    int partial = 0;
    for (int i = tid; i < b; i += 256) partial += sbp[i];
    s[tid] = (unsigned)partial;
    __syncthreads();
    for (int d = 128; d > 0; d >>= 1) {
        if (tid < d) s[tid] += s[tid + d];
        __syncthreads();
    }
    if (tid == 0) se0 = (int)s[0];
    __syncthreads();
    int e0 = se0;
    int cntb = sbp[b];
    const ull* st = staging + (size_t)b * CAPB;
    for (int i = tid; i < cntb; i += 256) {
        ull rec = st[i];
        unsigned cl = (unsigned)(rec >> 32) & 255u;
        atomicAdd(&cnt[cl], 1u);
        atomicAdd(&degq[cl], (unsigned)rec & 32767u);
    }
    __syncthreads();
    unsigned v = cnt[tid];
    s[tid] = v;
    __syncthreads();
    for (int d = 1; d < 256; d <<= 1) {
        unsigned t = (tid >= d) ? s[tid - d] : 0;
        __syncthreads();
        s[tid] += t;
        __syncthreads();
    }
    int colg = (b << 8) + tid;
    float dv = 0.f;
    if (colg < N_NODES) {
        off[colg] = e0 + (int)s[tid];  // segment END
        float deg = (float)degq[tid] * (1.0f / 32768.0f);
        dv = deg > 0.f ? 1.0f / sqrtf(deg) : 0.f;
        dinv[colg] = dv;
    }
    sdv[tid] = dv;
    wptr[tid] = e0 + (int)s[tid] - (int)v;  // exclusive start
    __syncthreads();
    for (int i = tid; i < cntb; i += 256) {
        ull rec = st[i];
        unsigned cl = (unsigned)(rec >> 32) & 255u;
        int pos = atomicAdd(&wptr[cl], 1);
        ed[pos] = (unsigned)rec;  // low 32 bits = r<<15 | q15
    }
    // fused xs: 256 nodes x 16 bf16-pairs
    int nb0 = b << 8;
    for (int idx = tid; idx < 256 * 16; idx += 256) {
        int n = idx >> 4, c = idx & 15;
        int gn = nb0 + n;
        if (gn >= N_NODES) break;
        float d = sdv[n];
        xs[(size_t)gn * 16 + c] = packbf(x[(size_t)gn * 32 + 2 * c] * d,
                                         x[(size_t)gn * 32 + 2 * c + 1] * d);
    }
}

// ---------- gath32_dual with activeset tail blocks (blocks >= G32) ----------
__global__ __launch_bounds__(256) void gath32a_k(const unsigned* __restrict__ ed,
                                                 const int* __restrict__ off,
                                                 const float* __restrict__ dinv,
                                                 const uint4* __restrict__ src4,
                                                 uint4* __restrict__ p4,
                                                 uint4* __restrict__ u4,
                                                 int* __restrict__ mark,
                                                 int* __restrict__ list,
                                                 int* __restrict__ cnt) {
    if (blockIdx.x >= G32) {
        int e = (blockIdx.x - G32) * 256 + threadIdx.x;
        int end = off[NUM_APS - 1];
        if (e < end) {
            int r = (int)rec_r(ed[e]);
            if (atomicExch(&mark[r], 1) == 0) {
                int pos = atomicAdd(cnt, 1);
                if (pos < LISTCAP) list[pos] = r;
            }
        }
        return;
    }
    int t = blockIdx.x * 256 + threadIdx.x;
    int n = t >> 2;
    if (n >= N_NODES) return;
    int qd = t & 3;
    int s = (n == 0) ? 0 : off[n - 1];
    int e = off[n];
    float aA[8] = {0,0,0,0,0,0,0,0};
    float aB[8] = {0,0,0,0,0,0,0,0};
    float aC[8] = {0,0,0,0,0,0,0,0};
    float aD[8] = {0,0,0,0,0,0,0,0};
    int i = s;
    for (; i + 4 <= e; i += 4) {
        unsigned v0 = ed[i], v1 = ed[i + 1], v2 = ed[i + 2], v3 = ed[i + 3];
        uint4 s0 = src4[rec_r(v0) * 4 + qd];
        uint4 s1 = src4[rec_r(v1) * 4 + qd];
        uint4 s2 = src4[rec_r(v2) * 4 + qd];
        uint4 s3 = src4[rec_r(v3) * 4 + qd];
        float w0 = rec_w(v0), w1 = rec_w(v1), w2 = rec_w(v2), w3 = rec_w(v3);
        aA[0] += w0 * blo(s0.x); aA[1] += w0 * bhi(s0.x);
        aA[2] += w0 * blo(s0.y); aA[3] += w0 * bhi(s0.y);
        aA[4] += w0 * blo(s0.z); aA[5] += w0 * bhi(s0.z);
        aA[6] += w0 * blo(s0.w); aA[7] += w0 * bhi(s0.w);
        aB[0] += w1 * blo(s1.x); aB[1] += w1 * bhi(s1.x);
        aB[2] += w1 * blo(s1.y); aB[3] += w1 * bhi(s1.y);
        aB[4] += w1 * blo(s1.z); aB[5] += w1 * bhi(s1.z);
        aB[6] += w1 * blo(s1.w); aB[7] += w1 * bhi(s1.w);
        aC[0] += w2 * blo(s2.x); aC[1] += w2 * bhi(s2.x);
        aC[2] += w2 * blo(s2.y); aC[3] += w2 * bhi(s2.y);
        aC[4] += w2 * blo(s2.z); aC[5] += w2 * bhi(s2.z);
        aC[6] += w2 * blo(s2.w); aC[7] += w2 * bhi(s2.w);
        aD[0] += w3 * blo(s3.x); aD[1] += w3 * bhi(s3.x);
        aD[2] += w3 * blo(s3.y); aD[3] += w3 * bhi(s3.y);
        aD[4] += w3 * blo(s3.z); aD[5] += w3 * bhi(s3.z);
        aD[6] += w3 * blo(s3.w); aD[7] += w3 * bhi(s3.w);
    }
    for (; i < e; ++i) {
        unsigned v = ed[i];
        uint4 sv = src4[rec_r(v) * 4 + qd];
        float w = rec_w(v);
        aA[0] += w * blo(sv.x); aA[1] += w * bhi(sv.x);
        aA[2] += w * blo(sv.y); aA[3] += w * bhi(sv.y);
        aA[4] += w * blo(sv.z); aA[5] += w * bhi(sv.z);
        aA[6] += w * blo(sv.w); aA[7] += w * bhi(sv.w);
    }
#pragma unroll
    for (int k = 0; k < 8; ++k) aA[k] += aB[k] + aC[k] + aD[k];
    float d = dinv[n], d2 = d * d;
    p4[n * 4 + qd] = make_uint4(packbf(d * aA[0], d * aA[1]), packbf(d * aA[2], d * aA[3]),
                                packbf(d * aA[4], d * aA[5]), packbf(d * aA[6], d * aA[7]));
    u4[n * 4 + qd] = make_uint4(packbf(d2 * aA[0], d2 * aA[1]), packbf(d2 * aA[2], d2 * aA[3]),
                                packbf(d2 * aA[4], d2 * aA[5]), packbf(d2 * aA[6], d2 * aA[7]));
}

__global__ __launch_bounds__(256) void gath32_one_k(const unsigned* __restrict__ ed,
                                                    const int* __restrict__ off,
                                                    const float* __restrict__ dinv,
                                                    const uint4* __restrict__ src4,
                                                    uint4* __restrict__ p4, int nn) {
    int t = blockIdx.x * 256 + threadIdx.x;
    int n = t >> 2;
    if (n >= nn) return;
    int qd = t & 3;
    int s = (n == 0) ? 0 : off[n - 1];
    int e = off[n];
    float aA[8] = {0,0,0,0,0,0,0,0};
    float aB[8] = {0,0,0,0,0,0,0,0};
    float aC[8] = {0,0,0,0,0,0,0,0};
    float aD[8] = {0,0,0,0,0,0,0,0};
    int i = s;
    for (; i + 4 <= e; i += 4) {
        unsigned v0 = ed[i], v1 = ed[i + 1], v2 = ed[i + 2], v3 = ed[i + 3];
        uint4 s0 = src4[rec_r(v0) * 4 + qd];
        uint4 s1 = src4[rec_r(v1) * 4 + qd];
        uint4 s2 = src4[rec_r(v2) * 4 + qd];
        uint4 s3 = src4[rec_r(v3) * 4 + qd];
        float w0 = rec_w(v0), w1 = rec_w(v1), w2 = rec_w(v2), w3 = rec_w(v3);
        aA[0] += w0 * blo(s0.x); aA[1] += w0 * bhi(s0.x);
        aA[2] += w0 * blo(s0.y); aA[3] += w0 * bhi(s0.y);
        aA[4] += w0 * blo(s0.z); aA[5] += w0 * bhi(s0.z);
        aA[6] += w0 * blo(s0.w); aA[7] += w0 * bhi(s0.w);
        aB[0] += w1 * blo(s1.x); aB[1] += w1 * bhi(s1.x);
        aB[2] += w1 * blo(s1.y); aB[3] += w1 * bhi(s1.y);
        aB[4] += w1 * blo(s1.z); aB[5] += w1 * bhi(s1.z);
        aB[6] += w1 * blo(s1.w); aB[7] += w1 * bhi(s1.w);
        aC[0] += w2 * blo(s2.x); aC[1] += w2 * bhi(s2.x);
        aC[2] += w2 * blo(s2.y); aC[3] += w2 * bhi(s2.y);
        aC[4] += w2 * blo(s2.z); aC[5] += w2 * bhi(s2.z);
        aC[6] += w2 * blo(s2.w); aC[7] += w2 * bhi(s2.w);
        aD[0] += w3 * blo(s3.x); aD[1] += w3 * bhi(s3.x);
        aD[2] += w3 * blo(s3.y); aD[3] += w3 * bhi(s3.y);
        aD[4] += w3 * blo(s3.z); aD[5] += w3 * bhi(s3.z);
        aD[6] += w3 * blo(s3.w); aD[7] += w3 * bhi(s3.w);
    }
    for (; i < e; ++i) {
        unsigned v = ed[i];
        uint4 sv = src4[rec_r(v) * 4 + qd];
        float w = rec_w(v);
        aA[0] += w * blo(sv.x); aA[1] += w * bhi(sv.x);
        aA[2] += w * blo(sv.y); aA[3] += w * bhi(sv.y);
        aA[4] += w * blo(sv.z); aA[5] += w * bhi(sv.z);
        aA[6] += w * blo(sv.w); aA[7] += w * bhi(sv.w);
    }
#pragma unroll
    for (int k = 0; k < 8; ++k) aA[k] += aB[k] + aC[k] + aD[k];
    float d = dinv[n];
    p4[n * 4 + qd] = make_uint4(packbf(d * aA[0], d * aA[1]), packbf(d * aA[2], d * aA[3]),
                                packbf(d * aA[4], d * aA[5]), packbf(d * aA[6], d * aA[7]));
}

// ---------- fused layer-2 first hop (verbatim round 21) ----------
__global__ __launch_bounds__(256) void gath64_l2_k(const unsigned* __restrict__ ed,
                                                   const int* __restrict__ off,
                                                   const float* __restrict__ dinv,
                                                   const unsigned* __restrict__ src,
                                                   const int* __restrict__ list,
                                                   const int* __restrict__ cnt,
                                                   unsigned* __restrict__ u,
                                                   unsigned* __restrict__ q) {
    int t = blockIdx.x * 256 + threadIdx.x;
    int idx = t >> 5;
    int fp = t & 31;
    int n;
    bool wq;
    if (idx < NUM_APS) {
        n = idx;
        wq = true;
    } else {
        int j = idx - NUM_APS;
        int c = *cnt;
        if (c > LISTCAP) c = LISTCAP;
        if (j >= c) return;
        n = list[j];
        wq = false;
    }
    int s = (n == 0) ? 0 : off[n - 1];
    int e = off[n];
    float a0 = 0.f, a1 = 0.f, b0 = 0.f, b1 = 0.f;
    int i = s;
    for (; i + 4 <= e; i += 4) {
        unsigned v0 = ed[i], v1 = ed[i + 1], v2 = ed[i + 2], v3 = ed[i + 3];
        unsigned s0 = src[rec_r(v0) * 32 + fp];
        unsigned s1 = src[rec_r(v1) * 32 + fp];
        unsigned s2 = src[rec_r(v2) * 32 + fp];
        unsigned s3 = src[rec_r(v3) * 32 + fp];
        float w0 = rec_w(v0), w1 = rec_w(v1), w2 = rec_w(v2), w3 = rec_w(v3);
        a0 += w0 * blo(s0); a1 += w0 * bhi(s0);
        b0 += w1 * blo(s1); b1 += w1 * bhi(s1);
        a0 += w2 * blo(s2); a1 += w2 * bhi(s2);
        b0 += w3 * blo(s3); b1 += w3 * bhi(s3);
    }
    for (; i < e; ++i) {
        unsigned v = ed[i];
        unsigned sv = src[rec_r(v) * 32 + fp];
        float w = rec_w(v);
        a0 += w * blo(sv); a1 += w * bhi(sv);
    }
    a0 += b0; a1 += b1;
    float d = dinv[n], d2 = d * d;
    u[n * 32 + fp] = packbf(d2 * a0, d2 * a1);
    if (wq) q[n * 32 + fp] = packbf(d * a0, d * a1);
}

// ---------- dense layer 1 on MFMA (verbatim round 15/21, verified) ----------
__global__ __launch_bounds__(256) void dense1m_k(const float* __restrict__ x,
                                                 const unsigned* __restrict__ p1,
                                                 const unsigned* __restrict__ p2,
                                                 const float* __restrict__ w,
                                                 const float* __restrict__ b,
                                                 const float* __restrict__ dinv,
                                                 bf16* __restrict__ h1s,
                                                 bf16* __restrict__ h1p) {
    __shared__ short sxb[64 * 104];   // inputs bf16 [node][k], 13.3 KB
    __shared__ short swt[64 * 104];   // weights^T bf16 [col][k], 13.3 KB
    __shared__ float sbias[64];
    __shared__ float sdv[64];
    int tid = threadIdx.x;
    int nb = blockIdx.x * 64;
    for (int idx = tid; idx < 96 * 64; idx += 256) {
        int j = idx >> 6, f = idx & 63;
        swt[f * 104 + j] = f2bs(w[idx]);
    }
    for (int i = tid; i < 64 * 16; i += 256) {
        int n = i >> 4, c = i & 15;
        int gn = nb + n;
        float v0 = 0.f, v1 = 0.f;
        if (gn < N_NODES) {
            v0 = x[(size_t)gn * 32 + 2 * c];
            v1 = x[(size_t)gn * 32 + 2 * c + 1];
        }
        ((unsigned*)sxb)[n * 52 + c] = packbf(v0, v1);
    }
    for (int i = tid; i < 64 * 16; i += 256) {
        int n = i >> 4, c = i & 15;
        int gn = nb + n;
        unsigned v1 = 0u, v2 = 0u;
        if (gn < N_NODES) {
            v1 = p1[(size_t)gn * 16 + c];
            v2 = p2[(size_t)gn * 16 + c];
        }
        ((unsigned*)sxb)[n * 52 + 16 + c] = v1;
        ((unsigned*)sxb)[n * 52 + 32 + c] = v2;
    }
    if (tid < 64) {
        sbias[tid] = b[tid];
        int gn = nb + tid;
        sdv[tid] = (gn < N_NODES) ? dinv[gn] : 0.f;
    }
    __syncthreads();

    int lane = tid & 63;
    int wt = tid >> 6;
    int lr = lane & 15;
    int kg = lane >> 4;
    const short* arow = &sxb[(wt * 16 + lr) * 104 + kg * 8];
    bf16x8 a0 = *(const bf16x8*)(arow);
    bf16x8 a1 = *(const bf16x8*)(arow + 32);
    bf16x8 a2 = *(const bf16x8*)(arow + 64);
#pragma unroll
    for (int ct = 0; ct < 4; ++ct) {
        const short* bcol = &swt[(ct * 16 + lr) * 104 + kg * 8];
        bf16x8 b0 = *(const bf16x8*)(bcol);
        bf16x8 b1 = *(const bf16x8*)(bcol + 32);
        bf16x8 b2 = *(const bf16x8*)(bcol + 64);
        f32x4 acc = {0.f, 0.f, 0.f, 0.f};
        acc = __builtin_amdgcn_mfma_f32_16x16x32_bf16(a0, b0, acc, 0, 0, 0);
        acc = __builtin_amdgcn_mfma_f32_16x16x32_bf16(a1, b1, acc, 0, 0, 0);
        acc = __builtin_amdgcn_mfma_f32_16x16x32_bf16(a2, b2, acc, 0, 0, 0);
        int colo = ct * 16 + lr;
        float bias = sbias[colo];
#pragma unroll
        for (int r = 0; r < 4; ++r) {
            int rowl = wt * 16 + kg * 4 + r;
            int gn = nb + rowl;
            if (gn < N_NODES) {
                float a = acc[r] + bias;
                a = a > 0.f ? a : 0.01f * a;
                h1s[(size_t)gn * HID + colo] = __float2bfloat16(a * sdv[rowl]);
                if (gn < NUM_APS) h1p[(size_t)gn * HID + colo] = __float2bfloat16(a);
            }
        }
    }
}

// dense2 + fused q2 gather + fused logits heads. Grid = 250 blocks x 4 AP nodes
// (all nodes < NUM_APS). Lanes (tid&63)<32 gather q2 from u3 straight into LDS.
__global__ __launch_bounds__(256) void dense2g_k(const bf16* __restrict__ h1p,
                                                 const bf16* __restrict__ q1,
                                                 const unsigned* __restrict__ u3,
                                                 const unsigned* __restrict__ ed,
                                                 const int* __restrict__ off,
                                                 const float* __restrict__ dinv,
                                                 const float* __restrict__ w,
                                                 const float* __restrict__ b,
                                                 const float* __restrict__ wch,
                                                 const float* __restrict__ bch,
                                                 const float* __restrict__ wpw,
                                                 const float* __restrict__ bpw,
                                                 float* __restrict__ out) {
    __shared__ float sw[3 * HID * HID];  // 48 KB
    __shared__ float sx[4][3 * HID];
    __shared__ float sap[4][HID];
    int tid = threadIdx.x;
    for (int i = tid; i < 3 * HID * HID; i += 256) sw[i] = w[i];
    int nb = blockIdx.x * 4;
    // stage h1p | q1 (first 128 cols)
    for (int k = tid; k < 4 * 128; k += 256) {
        int ln = k >> 7, j = k & 127;
        int n = nb + ln;
        const bf16* sp = (j < 64) ? h1p : q1;
        sx[ln][j] = b2f(sp[n * HID + (j & 63)]);
    }
    // fused q2 gather: lanes (tid&63)<32, fp = lane, node = nb + (tid>>6)
    {
        int ln = tid >> 6;
        int half = tid & 63;
        if (half < 32) {
            int n = nb + ln;
            int fp = half;
            int s0 = (n == 0) ? 0 : off[n - 1];
            int e = off[n];
            float a0 = 0.f, a1 = 0.f;
            for (int i = s0; i < e; ++i) {
                unsigned v = ed[i];
                unsigned sv = u3[rec_r(v) * 32 + fp];
                float wq = rec_w(v);
                a0 += wq * blo(sv);
                a1 += wq * bhi(sv);
            }
            float d = dinv[n];
            sx[ln][128 + 2 * fp]     = d * a0;
            sx[ln][128 + 2 * fp + 1] = d * a1;
        }
    }
    __syncthreads();
    int ln = tid >> 6;
    int f = tid & 63;
    float acc = b[f];
#pragma unroll 8
    for (int j = 0; j < 192; ++j) acc += sx[ln][j] * sw[j * HID + f];
    acc = acc > 0.f ? acc : 0.01f * acc;
    sap[ln][f] = acc;
    __syncthreads();
    if (tid < 24) {
        int lnn = tid / 6, j = tid % 6;
        int n = nb + lnn;
        const float* wp;
        float bb;
        float* o;
        if (j < 3) {
            wp = wch + j; bb = bch[j]; o = out + n * 3 + j;
        } else {
            int jj = j - 3;
            wp = wpw + jj; bb = bpw[jj]; o = out + NUM_APS * 3 + n * 3 + jj;
        }
        float a = bb;
#pragma unroll
        for (int i = 0; i < HID; ++i) a += sap[lnn][i] * wp[i * 3];
        *o = a;
    }
}

extern "C" void kernel_launch(void* const* d_in, const int* in_sizes, int n_in,
                              void* d_out, int out_size, void* d_ws, size_t ws_size,
                              hipStream_t stream) {
    const float* x   = (const float*)d_in[0];
    const int*   ei  = (const int*)d_in[1];
    const float* ea  = (const float*)d_in[2];
    const float* w1  = (const float*)d_in[3];
    const float* b1  = (const float*)d_in[4];
    const float* w2  = (const float*)d_in[5];
    const float* b2  = (const float*)d_in[6];
    const float* wch = (const float*)d_in[7];
    const float* bch = (const float*)d_in[8];
    const float* wpw = (const float*)d_in[9];
    const float* bpw = (const float*)d_in[10];

    const int E = in_sizes[2];  // 1,600,000
    const int* row  = ei;
    const int* colv = ei + E;

    // ---- workspace layout (4-byte units), ~48.5 MB (round 21 base; binBase removed) ----
    float* ws = (float*)d_ws;
    ull*      staging = (ull*)ws;                     // [0, 3,603,456)
    unsigned* ed      = (unsigned*)(ws + 3700000);    // [3.7M, 5.3M)
    int*      binPtr  = (int*)(ws + 5300000);         // 512
    int*      acnt    = (int*)(ws + 5300512);         // 1
    int*      mark    = (int*)(ws + 5300513);         // 100,000
    int*      off     = (int*)(ws + 5402048);         // +100,000
    float*    dinv    = ws + 5502048;                 // +100,000
    unsigned* xs      = (unsigned*)(ws + 5602048);    // 1.6M (16B-aligned)
    unsigned* u1      = xs + 1600000;                 // 1.6M
    unsigned* p1      = (unsigned*)(ws + 8802048);    // 1.6M (16B-aligned)
    unsigned* p2      = p1 + 1600000;                 // 1.6M
    unsigned* h1s     = xs;                           // overlays xs∪u1 (3.2M)
    unsigned* u3      = p1;                           // overlays p1∪p2 (3.2M)
    bf16*     h1p     = (bf16*)(ws + 12002048);       // 64,000 bf16
    bf16*     q1      = (bf16*)(ws + 12034048);       // 64,000 bf16
    int*      alist   = (int*)(ws + 12098048);        // LISTCAP ints

    const int gridE = (E + EPB - 1) / EPB;  // 391

    // ---- custom zero: binPtr + acnt + mark ----
    zero_k<<<(ZERON + 255) / 256, 256, 0, stream>>>(binPtr);

    // ---- CSR build (binscan fused into binfin3) ----
    binwrite2_k<<<gridE, 512, 0, stream>>>(row, colv, ea, binPtr, staging, E);
    binfin3_k<<<NB, 256, 0, stream>>>(staging, binPtr, x, ed, off, dinv, xs);

    // ---- layer 1 (activeset fused as tail blocks) ----
    gath32a_k<<<G32 + ACTB, 256, 0, stream>>>(ed, off, dinv, (const uint4*)xs,
                                              (uint4*)p1, (uint4*)u1,
                                              mark, alist, acnt);
    gath32_one_k<<<(N_NODES * 4 + 255) / 256, 256, 0, stream>>>(ed, off, dinv,
                                                                (const uint4*)u1,
                                                                (uint4*)p2, N_NODES);
    dense1m_k<<<(N_NODES + 63) / 64, 256, 0, stream>>>(x, p1, p2, w1, b1, dinv,
                                                       (bf16*)h1s, h1p);

    // ---- layer 2: fused first hop, then dense2 (+q2 gather +heads) ----
    gath64_l2_k<<<((NUM_APS + LISTCAP) * 32 + 255) / 256, 256, 0, stream>>>(
        ed, off, dinv, h1s, alist, acnt, u3, (unsigned*)q1);
    dense2g_k<<<NUM_APS / 4, 256, 0, stream>>>(h1p, q1, u3, ed, off, dinv, w2, b2,
                                               wch, bch, wpw, bpw, (float*)d_out);
}